// Round 1
// baseline (53.688 us; speedup 1.0000x reference)
//
#include <hip/hip_runtime.h>

// BurstCoding: out[b,t,s] = ((t % period) < burst_length) && ((t / period) < floor(clip(x[b,s],0,1)*max_bursts))
// x: [B=16, 3, 224, 224] f32, out: [B, T=32, 3, 224, 224] f32.
// Memory-bound: 308 MB write + 9.6 MB read. One thread per input float4,
// reads x once, writes T float4 planes (coalesced within each plane).

__global__ __launch_bounds__(256) void burst_coding_kernel(
    const float* __restrict__ x, float* __restrict__ out,
    const int* __restrict__ p_bl, const int* __restrict__ p_ibi,
    int T, int S4, long total4)
{
    const int bl     = *p_bl;               // burst_length (broadcast scalar load)
    const int period = bl + *p_ibi;         // burst_length + interburst_interval
    const int maxb   = T / period;
    const float mbf  = (float)maxb;

    for (long i = blockIdx.x * (long)blockDim.x + threadIdx.x; i < total4;
         i += (long)gridDim.x * blockDim.x) {
        const long b  = i / S4;             // batch index
        const int  s4 = (int)(i - b * S4);  // float4 index within spatial plane

        const float4 xv = reinterpret_cast<const float4*>(x)[i];

        // n_bursts = floor(clip(x,0,1) * max_bursts); trunc == floor for nonneg
        const int n0 = (int)(fminf(fmaxf(xv.x, 0.f), 1.f) * mbf);
        const int n1 = (int)(fminf(fmaxf(xv.y, 0.f), 1.f) * mbf);
        const int n2 = (int)(fminf(fmaxf(xv.z, 0.f), 1.f) * mbf);
        const int n3 = (int)(fminf(fmaxf(xv.w, 0.f), 1.f) * mbf);

        float4* outp = reinterpret_cast<float4*>(out) + b * (long)T * S4 + s4;

        int tmod = 0, bidx = 0;
        for (int t = 0; t < T; ++t) {
            const bool w = (tmod < bl);
            float4 v;
            v.x = (w && (bidx < n0)) ? 1.f : 0.f;
            v.y = (w && (bidx < n1)) ? 1.f : 0.f;
            v.z = (w && (bidx < n2)) ? 1.f : 0.f;
            v.w = (w && (bidx < n3)) ? 1.f : 0.f;
            outp[(long)t * S4] = v;
            if (++tmod == period) { tmod = 0; ++bidx; }
        }
    }
}

extern "C" void kernel_launch(void* const* d_in, const int* in_sizes, int n_in,
                              void* d_out, int out_size, void* d_ws, size_t ws_size,
                              hipStream_t stream) {
    const float* x   = (const float*)d_in[0];
    // d_in[1] = timesteps (derived on host from sizes instead)
    const int* p_bl  = (const int*)d_in[2];  // burst_length
    const int* p_ibi = (const int*)d_in[3];  // interburst_interval
    float* out = (float*)d_out;

    const long N  = (long)in_sizes[0];       // B * S = 16 * 150528
    const int  T  = (int)((long)out_size / N);  // = 32
    const int  S  = 3 * 224 * 224;           // spatial elems per batch (from reference setup)
    const int  S4 = S / 4;
    const long total4 = N / 4;

    const int threads = 256;
    const long blocks = (total4 + threads - 1) / threads;

    burst_coding_kernel<<<dim3((unsigned)blocks), dim3(threads), 0, stream>>>(
        x, out, p_bl, p_ibi, T, S4, total4);
}